// Round 5
// baseline (391.323 us; speedup 1.0000x reference)
//
#include <hip/hip_runtime.h>

typedef unsigned short u16;
typedef __attribute__((ext_vector_type(8))) short short8;
typedef __attribute__((ext_vector_type(4))) unsigned short ushort4v;
typedef __attribute__((ext_vector_type(4))) float float4v;

#define TVB 7500
#define CTVB 480000
#define XPAD_OFF 524288        // byte offset of x_pad in workspace
#define XPAD_U16 39321600ull   // 64*300*64*32 u16 elements

static __device__ __forceinline__ float bf2f(u16 a) {
    union { unsigned u; float f; } x; x.u = ((unsigned)a) << 16; return x.f;
}
static __device__ __forceinline__ u16 f2bf(float f) {
    union { float f; unsigned u; } x; x.f = f;
    unsigned r = x.u + 0x7fffu + ((x.u >> 16) & 1u);
    return (u16)(r >> 16);
}

// ---------------- Kernel A: attention score partials S_i[n,u,v] (+ x_pad emission) ----------------
// EXACT round-1-proven structure; xpad emission is the only addition.
// grid (15, 64), block 256. Each block: 20 t's (5 groups of 4).
__global__ __launch_bounds__(256, 3) void kA(
    const float* __restrict__ xg, const float* __restrict__ Wa, const float* __restrict__ ba,
    const float* __restrict__ Wb, const float* __restrict__ bb, float* __restrict__ Sws,
    u16* __restrict__ xpad)
{
    __shared__ u16 xT[4][32][72];   // xT[tt][u][c] : X_t transposed (B-operand for W@X)
    __shared__ u16 asT[3][32][72];  // a^T : [i][u][k=tt*16+ci]
    __shared__ u16 bsT[3][32][72];  // b^T : [i][v][k]
    const int tid  = threadIdx.x;
    const int lane = tid & 63;
    const int w    = tid >> 6;
    const int l15  = lane & 15;
    const int q    = lane >> 4;
    const int n    = blockIdx.y;
    const int t0   = blockIdx.x * 20;
    const bool emit = (xpad != nullptr);

    // zero the pad rows u=25..31 of xT once (never touched by staging)
    for (int e = tid; e < 4 * 7 * 72; e += 256) {
        int tt = e / (7 * 72);
        int r  = e - tt * (7 * 72);
        xT[tt][25 + r / 72][r % 72] = 0;
    }

    // Preload Wa/Wb A-frags (wave w<3 handles subset i=w). A[m=ci][k=c].
    short8 waf[2], wbf[2];
    float ba_r[4], bb_r[4];
    if (w < 3) {
        const float* wap = Wa + w * 1024;
        const float* wbp = Wb + w * 1024;
        #pragma unroll
        for (int kf = 0; kf < 2; ++kf) {
            short8 fa, fb;
            int base = l15 * 64 + kf * 32 + q * 8;
            #pragma unroll
            for (int j = 0; j < 8; ++j) {
                fa[j] = (short)f2bf(wap[base + j]);
                fb[j] = (short)f2bf(wbp[base + j]);
            }
            waf[kf] = fa; wbf[kf] = fb;
        }
        #pragma unroll
        for (int r = 0; r < 4; ++r) {
            ba_r[r] = ba[w * 16 + q * 4 + r];
            bb_r[r] = bb[w * 16 + q * 4 + r];
        }
    }

    float4v accS[3];
    #pragma unroll
    for (int i = 0; i < 3; ++i) accS[i] = (float4v){0.f, 0.f, 0.f, 0.f};

    const float* xb = xg + (size_t)n * CTVB;

    for (int g = 0; g < 5; ++g) {
        const size_t pbase = ((size_t)n * 300 + t0 + g * 4) * 2048;  // u16 units
        __syncthreads();
        // stage 4 t's, transposed, via float4 loads (round-1-proven); also emit
        // x_pad[n][t][c][32] from the same converted value.
        for (int e = tid; e < 1600; e += 256) {
            int c = e / 25;
            int j = e - c * 25;
            float4v xv = *(const float4v*)(xb + (size_t)c * TVB + (t0 + g * 4) * 25 + j * 4);
            #pragma unroll
            for (int k2 = 0; k2 < 4; ++k2) {
                int idx = j * 4 + k2;      // 0..99 = tt*25 + u
                int tt = idx / 25;
                int uu = idx - tt * 25;
                u16 h = f2bf(xv[k2]);
                xT[tt][uu][c] = h;
                if (emit) xpad[pbase + (size_t)tt * 2048 + c * 32 + uu] = h;
            }
        }
        // zero x_pad u-pads [25,32) for this group's 4*64 (tt,c) rows
        if (emit) {
            int tt = tid >> 6, c = tid & 63;
            u16* pp = xpad + pbase + (size_t)tt * 2048 + c * 32;
            #pragma unroll
            for (int z = 25; z < 32; ++z) pp[z] = 0;
        }
        __syncthreads();
        if (w < 3) {
            #pragma unroll
            for (int tt = 0; tt < 4; ++tt) {
                float4v aA0 = {0,0,0,0}, aA1 = {0,0,0,0}, aB0 = {0,0,0,0}, aB1 = {0,0,0,0};
                #pragma unroll
                for (int kf = 0; kf < 2; ++kf) {
                    short8 x0 = *(const short8*)&xT[tt][l15][kf * 32 + q * 8];
                    short8 x1 = *(const short8*)&xT[tt][16 + l15][kf * 32 + q * 8];
                    aA0 = __builtin_amdgcn_mfma_f32_16x16x32_bf16(waf[kf], x0, aA0, 0, 0, 0);
                    aA1 = __builtin_amdgcn_mfma_f32_16x16x32_bf16(waf[kf], x1, aA1, 0, 0, 0);
                    aB0 = __builtin_amdgcn_mfma_f32_16x16x32_bf16(wbf[kf], x0, aB0, 0, 0, 0);
                    aB1 = __builtin_amdgcn_mfma_f32_16x16x32_bf16(wbf[kf], x1, aB1, 0, 0, 0);
                }
                ushort4v pa0, pa1, pb0, pb1;
                #pragma unroll
                for (int r = 0; r < 4; ++r) {
                    pa0[r] = f2bf(aA0[r] + ba_r[r]);
                    pa1[r] = f2bf(aA1[r] + ba_r[r]);
                    pb0[r] = f2bf(aB0[r] + bb_r[r]);
                    pb1[r] = f2bf(aB1[r] + bb_r[r]);
                }
                int kb = tt * 16 + q * 4;   // k slot = tt*16 + ci, ci = q*4+r
                *(ushort4v*)&asT[w][l15][kb]      = pa0;
                *(ushort4v*)&asT[w][16 + l15][kb] = pa1;
                *(ushort4v*)&bsT[w][l15][kb]      = pb0;
                *(ushort4v*)&bsT[w][16 + l15][kb] = pb1;
            }
        }
        __syncthreads();
        // Stage 2: S_i += a^T b over this group's K=64. Wave -> (mt,nt) combo.
        const int mt = w >> 1, nt = w & 1;
        #pragma unroll
        for (int i = 0; i < 3; ++i) {
            #pragma unroll
            for (int ks = 0; ks < 2; ++ks) {
                short8 af  = *(const short8*)&asT[i][mt * 16 + l15][ks * 32 + q * 8];
                short8 bf_ = *(const short8*)&bsT[i][nt * 16 + l15][ks * 32 + q * 8];
                accS[i] = __builtin_amdgcn_mfma_f32_16x16x32_bf16(af, bf_, accS[i], 0, 0, 0);
            }
        }
    }
    const int mt = w >> 1, nt = w & 1;
    #pragma unroll
    for (int i = 0; i < 3; ++i) {
        #pragma unroll
        for (int r = 0; r < 4; ++r) {
            int u = mt * 16 + q * 4 + r;
            int v = nt * 16 + l15;
            if (u < 25 && v < 25)
                atomicAdd(&Sws[(i * 64 + n) * 625 + u * 25 + v], accS[i][r]);
        }
    }
}

// ---------------- Kernel S: softmax over u (dim -2), + A_static + graph_attn ----------------
__global__ __launch_bounds__(64) void kS(float* __restrict__ Sws,
    const float* __restrict__ Ast, const float* __restrict__ Gat)
{
    int g = blockIdx.x;       // g = i*64 + n
    int i = g >> 6;
    int v = threadIdx.x;
    if (v >= 25) return;
    float vals[25];
    float m = -1e30f;
    #pragma unroll
    for (int u = 0; u < 25; ++u) {
        float s = Sws[g * 625 + u * 25 + v] * (1.0f / 4800.0f);
        vals[u] = s;
        m = fmaxf(m, s);
    }
    float sum = 0.f;
    #pragma unroll
    for (int u = 0; u < 25; ++u) { float e = __expf(vals[u] - m); vals[u] = e; sum += e; }
    float isum = 1.f / sum;
    #pragma unroll
    for (int u = 0; u < 25; ++u) {
        int idx = i * 625 + u * 25 + v;
        Sws[g * 625 + u * 25 + v] = vals[u] * isum + Ast[idx] + Gat[idx];
    }
}

// ---------------- Kernel B2: round-1 kB with A-frags/residual from xpad ----------------
// grid (25, 64), block 256. 12 t's per block. LDS = 12800 + 6144 = 18944 B.
__global__ __launch_bounds__(256, 4) void kB2(
    const float* __restrict__ Wgp, const float* __restrict__ bgp,
    const float* __restrict__ gam, const float* __restrict__ bet, const float* __restrict__ rmu,
    const float* __restrict__ rva, const float* __restrict__ attnw, const u16* __restrict__ xpad,
    float* __restrict__ outg)
{
    __shared__ u16 ysT[32][200];     // Ycat^T : [v][k=i*64+c]
    __shared__ u16 pTs[3][32][32];   // attn^T : [i][v][u], zero-padded
    const int tid  = threadIdx.x;
    const int lane = tid & 63;
    const int w    = tid >> 6;
    const int l15  = lane & 15;
    const int q    = lane >> 4;
    const int n    = blockIdx.y;
    const int t0   = blockIdx.x * 12;

    for (int e = tid; e < 3 * 32 * 32; e += 256) ((u16*)pTs)[e] = 0;
    __syncthreads();
    for (int e = tid; e < 1875; e += 256) {
        int i = e / 625;
        int r = e - i * 625;
        int u = r / 25;
        int v = r - u * 25;
        pTs[i][v][u] = f2bf(attnw[(i * 64 + n) * 625 + r]);
    }
    // Wg A-frags in registers for the whole kernel. A[m=o][k=i*64+c]
    short8 wgf[6];
    const int o_row = w * 16 + l15;
    #pragma unroll
    for (int kf = 0; kf < 6; ++kf) {
        int i  = kf >> 1;
        int c0 = (kf & 1) * 32 + q * 8;
        const float* p = Wgp + i * 4096 + o_row * 64 + c0;
        short8 f;
        #pragma unroll
        for (int j = 0; j < 8; ++j) f[j] = (short)f2bf(p[j]);
        wgf[kf] = f;
    }
    // BN constants per lane (o = w*16 + q*4 + r)
    float invr[4], add0r[4];
    #pragma unroll
    for (int r = 0; r < 4; ++r) {
        int o = w * 16 + q * 4 + r;
        float gv = gam[o], bt = bet[o], mu = rmu[o], vv = rva[o];
        float bgs = bgp[o] + bgp[64 + o] + bgp[128 + o];
        float iv = gv * rsqrtf(vv + 1e-5f);
        invr[r] = iv;
        add0r[r] = (bgs - mu) * iv + bt;
    }
    __syncthreads();
    // P B-frags in registers: B[k=u][n=v]
    short8 pf[3][2];
    #pragma unroll
    for (int i = 0; i < 3; ++i)
        #pragma unroll
        for (int nt = 0; nt < 2; ++nt)
            pf[i][nt] = *(const short8*)&pTs[i][nt * 16 + l15][q * 8];

    const u16* xpn = xpad + (size_t)n * 300 * 2048;
    float* ob = outg + (size_t)n * CTVB;

    for (int tl = 0; tl < 12; ++tl) {
        const int t = t0 + tl;
        const u16* xp = xpn + (size_t)t * 2048;   // x_pad[n][t][c][32], MFMA-ready
        // Phase A: Y_i = X_t @ P_i  (A = x strip per wave, K=u padded 32)
        short8 xf = *(const short8*)&xp[(w * 16 + l15) * 32 + q * 8];
        #pragma unroll
        for (int i = 0; i < 3; ++i) {
            #pragma unroll
            for (int nt = 0; nt < 2; ++nt) {
                float4v acc = {0, 0, 0, 0};
                acc = __builtin_amdgcn_mfma_f32_16x16x32_bf16(xf, pf[i][nt], acc, 0, 0, 0);
                ushort4v pk;
                #pragma unroll
                for (int r = 0; r < 4; ++r) pk[r] = f2bf(acc[r]);
                *(ushort4v*)&ysT[nt * 16 + l15][i * 64 + w * 16 + q * 4] = pk;
            }
        }
        __syncthreads();
        // Phase B: Out_t = WgCat(64x192) @ Ycat(192x25pad32)
        #pragma unroll
        for (int nt = 0; nt < 2; ++nt) {
            float4v acc = {0, 0, 0, 0};
            #pragma unroll
            for (int kf = 0; kf < 6; ++kf) {
                short8 yf = *(const short8*)&ysT[nt * 16 + l15][kf * 32 + q * 8];
                acc = __builtin_amdgcn_mfma_f32_16x16x32_bf16(wgf[kf], yf, acc, 0, 0, 0);
            }
            int v = nt * 16 + l15;
            if (v < 25) {
                #pragma unroll
                for (int r = 0; r < 4; ++r) {
                    int o = w * 16 + q * 4 + r;
                    float xres = bf2f(xp[o * 32 + v]);   // residual from the same hot block
                    float val = fmaf(acc[r], invr[r], add0r[r]) + xres;
                    val = fmaxf(val, 0.f);
                    ob[(size_t)o * TVB + t * 25 + v] = val;
                }
            }
        }
        __syncthreads();
    }
}

// ---------------- Kernel B (fallback only): round-1 version ----------------
__global__ __launch_bounds__(256, 4) void kB(
    const float* __restrict__ xg, const float* __restrict__ Wgp, const float* __restrict__ bgp,
    const float* __restrict__ gam, const float* __restrict__ bet, const float* __restrict__ rmu,
    const float* __restrict__ rva, const float* __restrict__ attnw, float* __restrict__ outg)
{
    __shared__ u16 xsu[4][64][40];
    __shared__ u16 ysT[32][200];
    __shared__ u16 pTs[3][32][32];
    const int tid  = threadIdx.x;
    const int lane = tid & 63;
    const int w    = tid >> 6;
    const int l15  = lane & 15;
    const int q    = lane >> 4;
    const int n    = blockIdx.y;
    const int t0   = blockIdx.x * 4;

    for (int e = tid; e < 3 * 32 * 32; e += 256) ((u16*)pTs)[e] = 0;
    const float* xb = xg + (size_t)n * CTVB;
    for (int e = tid; e < 1600; e += 256) {
        int c = e / 25;
        int j = e - c * 25;
        float4v xv = *(const float4v*)(xb + (size_t)c * TVB + t0 * 25 + j * 4);
        #pragma unroll
        for (int k = 0; k < 4; ++k) {
            int idx = j * 4 + k;
            int tt = idx / 25;
            int u  = idx - tt * 25;
            xsu[tt][c][u] = f2bf(xv[k]);
        }
    }
    for (int e = tid; e < 4 * 64 * 7; e += 256) {
        int tt = e / (64 * 7);
        int r  = e - tt * (64 * 7);
        xsu[tt][r / 7][25 + r % 7] = 0;
    }
    __syncthreads();
    for (int e = tid; e < 1875; e += 256) {
        int i = e / 625;
        int r = e - i * 625;
        int u = r / 25;
        int v = r - u * 25;
        pTs[i][v][u] = f2bf(attnw[(i * 64 + n) * 625 + r]);
    }
    short8 wgf[6];
    const int o_row = w * 16 + l15;
    #pragma unroll
    for (int kf = 0; kf < 6; ++kf) {
        int i  = kf >> 1;
        int c0 = (kf & 1) * 32 + q * 8;
        const float* p = Wgp + i * 4096 + o_row * 64 + c0;
        short8 f;
        #pragma unroll
        for (int j = 0; j < 8; ++j) f[j] = (short)f2bf(p[j]);
        wgf[kf] = f;
    }
    float invr[4], add0r[4];
    #pragma unroll
    for (int r = 0; r < 4; ++r) {
        int o = w * 16 + q * 4 + r;
        float gv = gam[o], bt = bet[o], mu = rmu[o], vv = rva[o];
        float bgs = bgp[o] + bgp[64 + o] + bgp[128 + o];
        float iv = gv * rsqrtf(vv + 1e-5f);
        invr[r] = iv;
        add0r[r] = (bgs - mu) * iv + bt;
    }
    __syncthreads();
    short8 pf[3][2];
    #pragma unroll
    for (int i = 0; i < 3; ++i)
        #pragma unroll
        for (int nt = 0; nt < 2; ++nt)
            pf[i][nt] = *(const short8*)&pTs[i][nt * 16 + l15][q * 8];

    for (int tl = 0; tl < 4; ++tl) {
        short8 xf = *(const short8*)&xsu[tl][w * 16 + l15][q * 8];
        #pragma unroll
        for (int i = 0; i < 3; ++i) {
            #pragma unroll
            for (int nt = 0; nt < 2; ++nt) {
                float4v acc = {0, 0, 0, 0};
                acc = __builtin_amdgcn_mfma_f32_16x16x32_bf16(xf, pf[i][nt], acc, 0, 0, 0);
                ushort4v pk;
                #pragma unroll
                for (int r = 0; r < 4; ++r) pk[r] = f2bf(acc[r]);
                *(ushort4v*)&ysT[nt * 16 + l15][i * 64 + w * 16 + q * 4] = pk;
            }
        }
        __syncthreads();
        #pragma unroll
        for (int nt = 0; nt < 2; ++nt) {
            float4v acc = {0, 0, 0, 0};
            #pragma unroll
            for (int kf = 0; kf < 6; ++kf) {
                short8 yf = *(const short8*)&ysT[nt * 16 + l15][kf * 32 + q * 8];
                acc = __builtin_amdgcn_mfma_f32_16x16x32_bf16(wgf[kf], yf, acc, 0, 0, 0);
            }
            int v = nt * 16 + l15;
            if (v < 25) {
                size_t obp = (size_t)n * CTVB + (size_t)(t0 + tl) * 25 + v;
                #pragma unroll
                for (int r = 0; r < 4; ++r) {
                    int o = w * 16 + q * 4 + r;
                    float xres = bf2f(xsu[tl][o][v]);
                    float val = fmaf(acc[r], invr[r], add0r[r]) + xres;
                    val = fmaxf(val, 0.f);
                    outg[obp + (size_t)o * TVB] = val;
                }
            }
        }
        __syncthreads();
    }
}

extern "C" void kernel_launch(void* const* d_in, const int* in_sizes, int n_in,
                              void* d_out, int out_size, void* d_ws, size_t ws_size,
                              hipStream_t stream) {
    const float* x    = (const float*)d_in[0];
    const float* Ast  = (const float*)d_in[1];
    const float* Gat  = (const float*)d_in[2];
    const float* Wg   = (const float*)d_in[3];
    const float* bg   = (const float*)d_in[4];
    const float* Wa   = (const float*)d_in[5];
    const float* ba   = (const float*)d_in[6];
    const float* Wb   = (const float*)d_in[7];
    const float* bb   = (const float*)d_in[8];
    const float* gam  = (const float*)d_in[9];
    const float* bet  = (const float*)d_in[10];
    const float* rmu  = (const float*)d_in[11];
    const float* rva  = (const float*)d_in[12];
    float* out = (float*)d_out;
    float* Sws = (float*)d_ws;   // 192*625 floats = 480 KB

    const size_t need = (size_t)XPAD_OFF + XPAD_U16 * 2;
    hipMemsetAsync(Sws, 0, 192 * 625 * sizeof(float), stream);
    if (ws_size >= need) {
        u16* xpad = (u16*)((char*)d_ws + XPAD_OFF);
        kA<<<dim3(15, 64), 256, 0, stream>>>(x, Wa, ba, Wb, bb, Sws, xpad);
        kS<<<dim3(192), 64, 0, stream>>>(Sws, Ast, Gat);
        kB2<<<dim3(25, 64), 256, 0, stream>>>(Wg, bg, gam, bet, rmu, rva, Sws, xpad, out);
    } else {
        kA<<<dim3(15, 64), 256, 0, stream>>>(x, Wa, ba, Wb, bb, Sws, nullptr);
        kS<<<dim3(192), 64, 0, stream>>>(Sws, Ast, Gat);
        kB<<<dim3(75, 64), 256, 0, stream>>>(x, Wg, bg, gam, bet, rmu, rva, Sws, out);
    }
}

// Round 7
// 369.857 us; speedup vs baseline: 1.0580x; 1.0580x over previous
//
#include <hip/hip_runtime.h>

typedef unsigned short u16;
typedef __attribute__((ext_vector_type(8))) short short8;
typedef __attribute__((ext_vector_type(4))) unsigned short ushort4v;
typedef __attribute__((ext_vector_type(4))) float float4v;

#define TVB 7500
#define CTVB 480000
#define XPAD_OFF 524288        // byte offset of x_pad in workspace
#define XPAD_U16 39321600ull   // 64*300*64*32 u16 elements

static __device__ __forceinline__ float bf2f(u16 a) {
    union { unsigned u; float f; } x; x.u = ((unsigned)a) << 16; return x.f;
}
static __device__ __forceinline__ u16 f2bf(float f) {
    union { float f; unsigned u; } x; x.f = f;
    unsigned r = x.u + 0x7fffu + ((x.u >> 16) & 1u);
    return (u16)(r >> 16);
}

// ---------------- Kernel A: attention score partials S_i[n,u,v] (+ x_pad emission) ----------------
// Round-1-proven structure. xpad emission runs on the otherwise-idle wave 3
// during stage 1, sourced from the already-transposed xT in LDS (pad rows pre-zeroed).
// grid (15, 64), block 256. Each block: 20 t's (5 groups of 4).
__global__ __launch_bounds__(256, 3) void kA(
    const float* __restrict__ xg, const float* __restrict__ Wa, const float* __restrict__ ba,
    const float* __restrict__ Wb, const float* __restrict__ bb, float* __restrict__ Sws,
    u16* __restrict__ xpad)
{
    __shared__ u16 xT[4][32][72];   // xT[tt][u][c] : X_t transposed (B-operand for W@X)
    __shared__ u16 asT[3][32][72];  // a^T : [i][u][k=tt*16+ci]
    __shared__ u16 bsT[3][32][72];  // b^T : [i][v][k]
    const int tid  = threadIdx.x;
    const int lane = tid & 63;
    const int w    = tid >> 6;
    const int l15  = lane & 15;
    const int q    = lane >> 4;
    const int n    = blockIdx.y;
    const int t0   = blockIdx.x * 20;
    const bool emit = (xpad != nullptr);

    // zero the pad rows u=25..31 of xT once (never touched by staging; wave-3
    // emission reads them as the xpad u-pad zeros)
    for (int e = tid; e < 4 * 7 * 72; e += 256) {
        int tt = e / (7 * 72);
        int r  = e - tt * (7 * 72);
        xT[tt][25 + r / 72][r % 72] = 0;
    }

    // Preload Wa/Wb A-frags (wave w<3 handles subset i=w). A[m=ci][k=c].
    short8 waf[2], wbf[2];
    float ba_r[4], bb_r[4];
    if (w < 3) {
        const float* wap = Wa + w * 1024;
        const float* wbp = Wb + w * 1024;
        #pragma unroll
        for (int kf = 0; kf < 2; ++kf) {
            short8 fa, fb;
            int base = l15 * 64 + kf * 32 + q * 8;
            #pragma unroll
            for (int j = 0; j < 8; ++j) {
                fa[j] = (short)f2bf(wap[base + j]);
                fb[j] = (short)f2bf(wbp[base + j]);
            }
            waf[kf] = fa; wbf[kf] = fb;
        }
        #pragma unroll
        for (int r = 0; r < 4; ++r) {
            ba_r[r] = ba[w * 16 + q * 4 + r];
            bb_r[r] = bb[w * 16 + q * 4 + r];
        }
    }

    float4v accS[3];
    #pragma unroll
    for (int i = 0; i < 3; ++i) accS[i] = (float4v){0.f, 0.f, 0.f, 0.f};

    const float* xb = xg + (size_t)n * CTVB;

    for (int g = 0; g < 5; ++g) {
        const size_t pbase = ((size_t)n * 300 + t0 + g * 4) * 2048;  // u16 units
        __syncthreads();
        // stage 4 t's, transposed, via float4 loads (round-1-proven, no emission here)
        for (int e = tid; e < 1600; e += 256) {
            int c = e / 25;
            int j = e - c * 25;
            float4v xv = *(const float4v*)(xb + (size_t)c * TVB + (t0 + g * 4) * 25 + j * 4);
            #pragma unroll
            for (int k2 = 0; k2 < 4; ++k2) {
                int idx = j * 4 + k2;      // 0..99 = tt*25 + u
                int tt = idx / 25;
                int uu = idx - tt * 25;
                xT[tt][uu][c] = f2bf(xv[k2]);
            }
        }
        __syncthreads();
        if (w < 3) {
            #pragma unroll
            for (int tt = 0; tt < 4; ++tt) {
                float4v aA0 = {0,0,0,0}, aA1 = {0,0,0,0}, aB0 = {0,0,0,0}, aB1 = {0,0,0,0};
                #pragma unroll
                for (int kf = 0; kf < 2; ++kf) {
                    short8 x0 = *(const short8*)&xT[tt][l15][kf * 32 + q * 8];
                    short8 x1 = *(const short8*)&xT[tt][16 + l15][kf * 32 + q * 8];
                    aA0 = __builtin_amdgcn_mfma_f32_16x16x32_bf16(waf[kf], x0, aA0, 0, 0, 0);
                    aA1 = __builtin_amdgcn_mfma_f32_16x16x32_bf16(waf[kf], x1, aA1, 0, 0, 0);
                    aB0 = __builtin_amdgcn_mfma_f32_16x16x32_bf16(wbf[kf], x0, aB0, 0, 0, 0);
                    aB1 = __builtin_amdgcn_mfma_f32_16x16x32_bf16(wbf[kf], x1, aB1, 0, 0, 0);
                }
                ushort4v pa0, pa1, pb0, pb1;
                #pragma unroll
                for (int r = 0; r < 4; ++r) {
                    pa0[r] = f2bf(aA0[r] + ba_r[r]);
                    pa1[r] = f2bf(aA1[r] + ba_r[r]);
                    pb0[r] = f2bf(aB0[r] + bb_r[r]);
                    pb1[r] = f2bf(aB1[r] + bb_r[r]);
                }
                int kb = tt * 16 + q * 4;   // k slot = tt*16 + ci, ci = q*4+r
                *(ushort4v*)&asT[w][l15][kb]      = pa0;
                *(ushort4v*)&asT[w][16 + l15][kb] = pa1;
                *(ushort4v*)&bsT[w][l15][kb]      = pb0;
                *(ushort4v*)&bsT[w][16 + l15][kb] = pb1;
            }
        } else if (emit) {
            // wave 3 (idle in stage 1): emit x_pad[n][t][c][32] from xT.
            // lane = c; per tt: 32 conflict-free ds_read_u16 (rows 25..31 are the
            // pre-zeroed pads -> xpad u-pad zeros come free), 4x dwordx4 stores.
            const int c = lane;
            #pragma unroll
            for (int tt = 0; tt < 4; ++tt) {
                u16* dst = xpad + pbase + (size_t)tt * 2048 + c * 32;
                #pragma unroll
                for (int b = 0; b < 4; ++b) {
                    short8 ov;
                    #pragma unroll
                    for (int u = 0; u < 8; ++u)
                        ov[u] = (short)xT[tt][b * 8 + u][c];
                    *(short8*)(dst + b * 8) = ov;
                }
            }
        }
        __syncthreads();
        // Stage 2: S_i += a^T b over this group's K=64. Wave -> (mt,nt) combo.
        const int mt = w >> 1, nt = w & 1;
        #pragma unroll
        for (int i = 0; i < 3; ++i) {
            #pragma unroll
            for (int ks = 0; ks < 2; ++ks) {
                short8 af  = *(const short8*)&asT[i][mt * 16 + l15][ks * 32 + q * 8];
                short8 bf_ = *(const short8*)&bsT[i][nt * 16 + l15][ks * 32 + q * 8];
                accS[i] = __builtin_amdgcn_mfma_f32_16x16x32_bf16(af, bf_, accS[i], 0, 0, 0);
            }
        }
    }
    const int mt = w >> 1, nt = w & 1;
    #pragma unroll
    for (int i = 0; i < 3; ++i) {
        #pragma unroll
        for (int r = 0; r < 4; ++r) {
            int u = mt * 16 + q * 4 + r;
            int v = nt * 16 + l15;
            if (u < 25 && v < 25)
                atomicAdd(&Sws[(i * 64 + n) * 625 + u * 25 + v], accS[i][r]);
        }
    }
}

// ---------------- Kernel S: softmax over u (dim -2), + A_static + graph_attn ----------------
__global__ __launch_bounds__(64) void kS(float* __restrict__ Sws,
    const float* __restrict__ Ast, const float* __restrict__ Gat)
{
    int g = blockIdx.x;       // g = i*64 + n
    int i = g >> 6;
    int v = threadIdx.x;
    if (v >= 25) return;
    float vals[25];
    float m = -1e30f;
    #pragma unroll
    for (int u = 0; u < 25; ++u) {
        float s = Sws[g * 625 + u * 25 + v] * (1.0f / 4800.0f);
        vals[u] = s;
        m = fmaxf(m, s);
    }
    float sum = 0.f;
    #pragma unroll
    for (int u = 0; u < 25; ++u) { float e = __expf(vals[u] - m); vals[u] = e; sum += e; }
    float isum = 1.f / sum;
    #pragma unroll
    for (int u = 0; u < 25; ++u) {
        int idx = i * 625 + u * 25 + v;
        Sws[g * 625 + u * 25 + v] = vals[u] * isum + Ast[idx] + Gat[idx];
    }
}

// ---------------- Kernel B2: round-1 kB with A-frags/residual from xpad ----------------
// grid (25, 64), block 256. 12 t's per block. LDS = 12800 + 6144 = 18944 B.
__global__ __launch_bounds__(256, 4) void kB2(
    const float* __restrict__ Wgp, const float* __restrict__ bgp,
    const float* __restrict__ gam, const float* __restrict__ bet, const float* __restrict__ rmu,
    const float* __restrict__ rva, const float* __restrict__ attnw, const u16* __restrict__ xpad,
    float* __restrict__ outg)
{
    __shared__ u16 ysT[32][200];     // Ycat^T : [v][k=i*64+c]
    __shared__ u16 pTs[3][32][32];   // attn^T : [i][v][u], zero-padded
    const int tid  = threadIdx.x;
    const int lane = tid & 63;
    const int w    = tid >> 6;
    const int l15  = lane & 15;
    const int q    = lane >> 4;
    const int n    = blockIdx.y;
    const int t0   = blockIdx.x * 12;

    for (int e = tid; e < 3 * 32 * 32; e += 256) ((u16*)pTs)[e] = 0;
    __syncthreads();
    for (int e = tid; e < 1875; e += 256) {
        int i = e / 625;
        int r = e - i * 625;
        int u = r / 25;
        int v = r - u * 25;
        pTs[i][v][u] = f2bf(attnw[(i * 64 + n) * 625 + r]);
    }
    // Wg A-frags in registers for the whole kernel. A[m=o][k=i*64+c]
    short8 wgf[6];
    const int o_row = w * 16 + l15;
    #pragma unroll
    for (int kf = 0; kf < 6; ++kf) {
        int i  = kf >> 1;
        int c0 = (kf & 1) * 32 + q * 8;
        const float* p = Wgp + i * 4096 + o_row * 64 + c0;
        short8 f;
        #pragma unroll
        for (int j = 0; j < 8; ++j) f[j] = (short)f2bf(p[j]);
        wgf[kf] = f;
    }
    // BN constants per lane (o = w*16 + q*4 + r)
    float invr[4], add0r[4];
    #pragma unroll
    for (int r = 0; r < 4; ++r) {
        int o = w * 16 + q * 4 + r;
        float gv = gam[o], bt = bet[o], mu = rmu[o], vv = rva[o];
        float bgs = bgp[o] + bgp[64 + o] + bgp[128 + o];
        float iv = gv * rsqrtf(vv + 1e-5f);
        invr[r] = iv;
        add0r[r] = (bgs - mu) * iv + bt;
    }
    __syncthreads();
    // P B-frags in registers: B[k=u][n=v]
    short8 pf[3][2];
    #pragma unroll
    for (int i = 0; i < 3; ++i)
        #pragma unroll
        for (int nt = 0; nt < 2; ++nt)
            pf[i][nt] = *(const short8*)&pTs[i][nt * 16 + l15][q * 8];

    const u16* xpn = xpad + (size_t)n * 300 * 2048;
    float* ob = outg + (size_t)n * CTVB;

    for (int tl = 0; tl < 12; ++tl) {
        const int t = t0 + tl;
        const u16* xp = xpn + (size_t)t * 2048;   // x_pad[n][t][c][32], MFMA-ready
        // Phase A: Y_i = X_t @ P_i  (A = x strip per wave, K=u padded 32)
        short8 xf = *(const short8*)&xp[(w * 16 + l15) * 32 + q * 8];
        #pragma unroll
        for (int i = 0; i < 3; ++i) {
            #pragma unroll
            for (int nt = 0; nt < 2; ++nt) {
                float4v acc = {0, 0, 0, 0};
                acc = __builtin_amdgcn_mfma_f32_16x16x32_bf16(xf, pf[i][nt], acc, 0, 0, 0);
                ushort4v pk;
                #pragma unroll
                for (int r = 0; r < 4; ++r) pk[r] = f2bf(acc[r]);
                *(ushort4v*)&ysT[nt * 16 + l15][i * 64 + w * 16 + q * 4] = pk;
            }
        }
        __syncthreads();
        // Phase B: Out_t = WgCat(64x192) @ Ycat(192x25pad32)
        #pragma unroll
        for (int nt = 0; nt < 2; ++nt) {
            float4v acc = {0, 0, 0, 0};
            #pragma unroll
            for (int kf = 0; kf < 6; ++kf) {
                short8 yf = *(const short8*)&ysT[nt * 16 + l15][kf * 32 + q * 8];
                acc = __builtin_amdgcn_mfma_f32_16x16x32_bf16(wgf[kf], yf, acc, 0, 0, 0);
            }
            int v = nt * 16 + l15;
            if (v < 25) {
                #pragma unroll
                for (int r = 0; r < 4; ++r) {
                    int o = w * 16 + q * 4 + r;
                    float xres = bf2f(xp[o * 32 + v]);   // residual from the same hot block
                    float val = fmaf(acc[r], invr[r], add0r[r]) + xres;
                    val = fmaxf(val, 0.f);
                    ob[(size_t)o * TVB + t * 25 + v] = val;
                }
            }
        }
        __syncthreads();
    }
}

// ---------------- Kernel B (fallback only): round-1 version ----------------
__global__ __launch_bounds__(256, 4) void kB(
    const float* __restrict__ xg, const float* __restrict__ Wgp, const float* __restrict__ bgp,
    const float* __restrict__ gam, const float* __restrict__ bet, const float* __restrict__ rmu,
    const float* __restrict__ rva, const float* __restrict__ attnw, float* __restrict__ outg)
{
    __shared__ u16 xsu[4][64][40];
    __shared__ u16 ysT[32][200];
    __shared__ u16 pTs[3][32][32];
    const int tid  = threadIdx.x;
    const int lane = tid & 63;
    const int w    = tid >> 6;
    const int l15  = lane & 15;
    const int q    = lane >> 4;
    const int n    = blockIdx.y;
    const int t0   = blockIdx.x * 4;

    for (int e = tid; e < 3 * 32 * 32; e += 256) ((u16*)pTs)[e] = 0;
    const float* xb = xg + (size_t)n * CTVB;
    for (int e = tid; e < 1600; e += 256) {
        int c = e / 25;
        int j = e - c * 25;
        float4v xv = *(const float4v*)(xb + (size_t)c * TVB + t0 * 25 + j * 4);
        #pragma unroll
        for (int k = 0; k < 4; ++k) {
            int idx = j * 4 + k;
            int tt = idx / 25;
            int u  = idx - tt * 25;
            xsu[tt][c][u] = f2bf(xv[k]);
        }
    }
    for (int e = tid; e < 4 * 64 * 7; e += 256) {
        int tt = e / (64 * 7);
        int r  = e - tt * (64 * 7);
        xsu[tt][r / 7][25 + r % 7] = 0;
    }
    __syncthreads();
    for (int e = tid; e < 1875; e += 256) {
        int i = e / 625;
        int r = e - i * 625;
        int u = r / 25;
        int v = r - u * 25;
        pTs[i][v][u] = f2bf(attnw[(i * 64 + n) * 625 + r]);
    }
    short8 wgf[6];
    const int o_row = w * 16 + l15;
    #pragma unroll
    for (int kf = 0; kf < 6; ++kf) {
        int i  = kf >> 1;
        int c0 = (kf & 1) * 32 + q * 8;
        const float* p = Wgp + i * 4096 + o_row * 64 + c0;
        short8 f;
        #pragma unroll
        for (int j = 0; j < 8; ++j) f[j] = (short)f2bf(p[j]);
        wgf[kf] = f;
    }
    float invr[4], add0r[4];
    #pragma unroll
    for (int r = 0; r < 4; ++r) {
        int o = w * 16 + q * 4 + r;
        float gv = gam[o], bt = bet[o], mu = rmu[o], vv = rva[o];
        float bgs = bgp[o] + bgp[64 + o] + bgp[128 + o];
        float iv = gv * rsqrtf(vv + 1e-5f);
        invr[r] = iv;
        add0r[r] = (bgs - mu) * iv + bt;
    }
    __syncthreads();
    short8 pf[3][2];
    #pragma unroll
    for (int i = 0; i < 3; ++i)
        #pragma unroll
        for (int nt = 0; nt < 2; ++nt)
            pf[i][nt] = *(const short8*)&pTs[i][nt * 16 + l15][q * 8];

    for (int tl = 0; tl < 4; ++tl) {
        short8 xf = *(const short8*)&xsu[tl][w * 16 + l15][q * 8];
        #pragma unroll
        for (int i = 0; i < 3; ++i) {
            #pragma unroll
            for (int nt = 0; nt < 2; ++nt) {
                float4v acc = {0, 0, 0, 0};
                acc = __builtin_amdgcn_mfma_f32_16x16x32_bf16(xf, pf[i][nt], acc, 0, 0, 0);
                ushort4v pk;
                #pragma unroll
                for (int r = 0; r < 4; ++r) pk[r] = f2bf(acc[r]);
                *(ushort4v*)&ysT[nt * 16 + l15][i * 64 + w * 16 + q * 4] = pk;
            }
        }
        __syncthreads();
        #pragma unroll
        for (int nt = 0; nt < 2; ++nt) {
            float4v acc = {0, 0, 0, 0};
            #pragma unroll
            for (int kf = 0; kf < 6; ++kf) {
                short8 yf = *(const short8*)&ysT[nt * 16 + l15][kf * 32 + q * 8];
                acc = __builtin_amdgcn_mfma_f32_16x16x32_bf16(wgf[kf], yf, acc, 0, 0, 0);
            }
            int v = nt * 16 + l15;
            if (v < 25) {
                size_t obp = (size_t)n * CTVB + (size_t)(t0 + tl) * 25 + v;
                #pragma unroll
                for (int r = 0; r < 4; ++r) {
                    int o = w * 16 + q * 4 + r;
                    float xres = bf2f(xsu[tl][o][v]);
                    float val = fmaf(acc[r], invr[r], add0r[r]) + xres;
                    val = fmaxf(val, 0.f);
                    outg[obp + (size_t)o * TVB] = val;
                }
            }
        }
        __syncthreads();
    }
}

extern "C" void kernel_launch(void* const* d_in, const int* in_sizes, int n_in,
                              void* d_out, int out_size, void* d_ws, size_t ws_size,
                              hipStream_t stream) {
    const float* x    = (const float*)d_in[0];
    const float* Ast  = (const float*)d_in[1];
    const float* Gat  = (const float*)d_in[2];
    const float* Wg   = (const float*)d_in[3];
    const float* bg   = (const float*)d_in[4];
    const float* Wa   = (const float*)d_in[5];
    const float* ba   = (const float*)d_in[6];
    const float* Wb   = (const float*)d_in[7];
    const float* bb   = (const float*)d_in[8];
    const float* gam  = (const float*)d_in[9];
    const float* bet  = (const float*)d_in[10];
    const float* rmu  = (const float*)d_in[11];
    const float* rva  = (const float*)d_in[12];
    float* out = (float*)d_out;
    float* Sws = (float*)d_ws;   // 192*625 floats = 480 KB

    const size_t need = (size_t)XPAD_OFF + XPAD_U16 * 2;
    hipMemsetAsync(Sws, 0, 192 * 625 * sizeof(float), stream);
    if (ws_size >= need) {
        u16* xpad = (u16*)((char*)d_ws + XPAD_OFF);
        kA<<<dim3(15, 64), 256, 0, stream>>>(x, Wa, ba, Wb, bb, Sws, xpad);
        kS<<<dim3(192), 64, 0, stream>>>(Sws, Ast, Gat);
        kB2<<<dim3(25, 64), 256, 0, stream>>>(Wg, bg, gam, bet, rmu, rva, Sws, xpad, out);
    } else {
        kA<<<dim3(15, 64), 256, 0, stream>>>(x, Wa, ba, Wb, bb, Sws, nullptr);
        kS<<<dim3(192), 64, 0, stream>>>(Sws, Ast, Gat);
        kB<<<dim3(75, 64), 256, 0, stream>>>(x, Wg, bg, gam, bet, rmu, rva, Sws, out);
    }
}

// Round 8
// 344.940 us; speedup vs baseline: 1.1345x; 1.0722x over previous
//
#include <hip/hip_runtime.h>

typedef unsigned short u16;
typedef __attribute__((ext_vector_type(8))) short short8;
typedef __attribute__((ext_vector_type(4))) unsigned short ushort4v;
typedef __attribute__((ext_vector_type(4))) float float4v;

#define TVB 7500
#define CTVB 480000
#define XPAD_OFF 524288        // byte offset of x_pad in workspace
#define XPAD_U16 39321600ull   // 64*300*64*32 u16 elements

static __device__ __forceinline__ float bf2f(u16 a) {
    union { unsigned u; float f; } x; x.u = ((unsigned)a) << 16; return x.f;
}
static __device__ __forceinline__ u16 f2bf(float f) {
    union { float f; unsigned u; } x; x.f = f;
    unsigned r = x.u + 0x7fffu + ((x.u >> 16) & 1u);
    return (u16)(r >> 16);
}

// ---------------- Kernel A: attention score partials S_i[n,u,v] (+ x_pad emission) ----------------
// Round-7 structure + T14 async staging: group g+1's x loads are issued into
// registers while group g's MFMA/emission runs; loop-top barrier elided
// (staging writes xT only; stage2 reads asT/bsT only; post-stage1 barrier
// orders stage1's xT reads before the next group's xT writes).
// grid (15, 64), block 256. Each block: 20 t's (5 groups of 4).
__global__ __launch_bounds__(256, 3) void kA(
    const float* __restrict__ xg, const float* __restrict__ Wa, const float* __restrict__ ba,
    const float* __restrict__ Wb, const float* __restrict__ bb, float* __restrict__ Sws,
    u16* __restrict__ xpad)
{
    __shared__ u16 xT[4][32][72];   // xT[tt][u][c] : X_t transposed (B-operand for W@X)
    __shared__ u16 asT[3][32][72];  // a^T : [i][u][k=tt*16+ci]
    __shared__ u16 bsT[3][32][72];  // b^T : [i][v][k]
    const int tid  = threadIdx.x;
    const int lane = tid & 63;
    const int w    = tid >> 6;
    const int l15  = lane & 15;
    const int q    = lane >> 4;
    const int n    = blockIdx.y;
    const int t0   = blockIdx.x * 20;
    const bool emit = (xpad != nullptr);

    // zero the pad rows u=25..31 of xT once (never touched by staging; wave-3
    // emission reads them as the xpad u-pad zeros)
    for (int e = tid; e < 4 * 7 * 72; e += 256) {
        int tt = e / (7 * 72);
        int r  = e - tt * (7 * 72);
        xT[tt][25 + r / 72][r % 72] = 0;
    }

    // Preload Wa/Wb A-frags (wave w<3 handles subset i=w). A[m=ci][k=c].
    short8 waf[2], wbf[2];
    float ba_r[4], bb_r[4];
    if (w < 3) {
        const float* wap = Wa + w * 1024;
        const float* wbp = Wb + w * 1024;
        #pragma unroll
        for (int kf = 0; kf < 2; ++kf) {
            short8 fa, fb;
            int base = l15 * 64 + kf * 32 + q * 8;
            #pragma unroll
            for (int j = 0; j < 8; ++j) {
                fa[j] = (short)f2bf(wap[base + j]);
                fb[j] = (short)f2bf(wbp[base + j]);
            }
            waf[kf] = fa; wbf[kf] = fb;
        }
        #pragma unroll
        for (int r = 0; r < 4; ++r) {
            ba_r[r] = ba[w * 16 + q * 4 + r];
            bb_r[r] = bb[w * 16 + q * 4 + r];
        }
    }

    float4v accS[3];
    #pragma unroll
    for (int i = 0; i < 3; ++i) accS[i] = (float4v){0.f, 0.f, 0.f, 0.f};

    const float* xb = xg + (size_t)n * CTVB;

    // prefetch group 0 into registers (static-indexed reg array, rule #20)
    float4v pre[7];
    #pragma unroll
    for (int s = 0; s < 7; ++s) {
        int e = tid + (s << 8);
        if (e < 1600) {
            int c = e / 25, j = e - c * 25;
            pre[s] = *(const float4v*)(xb + (size_t)c * TVB + t0 * 25 + j * 4);
        }
    }

    for (int g = 0; g < 5; ++g) {
        const size_t pbase = ((size_t)n * 300 + t0 + g * 4) * 2048;  // u16 units
        // write phase: regs (group g) -> xT, transposed scatter
        #pragma unroll
        for (int s = 0; s < 7; ++s) {
            int e = tid + (s << 8);
            if (e < 1600) {
                int c = e / 25, j = e - c * 25;
                #pragma unroll
                for (int k2 = 0; k2 < 4; ++k2) {
                    int idx = j * 4 + k2;      // 0..99 = tt*25 + u
                    int tt = idx / 25;
                    int uu = idx - tt * 25;
                    xT[tt][uu][c] = f2bf(pre[s][k2]);
                }
            }
        }
        // issue group g+1 loads now; they complete under stage1+stage2 compute
        if (g < 4) {
            #pragma unroll
            for (int s = 0; s < 7; ++s) {
                int e = tid + (s << 8);
                if (e < 1600) {
                    int c = e / 25, j = e - c * 25;
                    pre[s] = *(const float4v*)(xb + (size_t)c * TVB + (t0 + (g + 1) * 4) * 25 + j * 4);
                }
            }
        }
        __syncthreads();   // staging (and, at g=0, pad-zero) complete
        if (w < 3) {
            #pragma unroll
            for (int tt = 0; tt < 4; ++tt) {
                float4v aA0 = {0,0,0,0}, aA1 = {0,0,0,0}, aB0 = {0,0,0,0}, aB1 = {0,0,0,0};
                #pragma unroll
                for (int kf = 0; kf < 2; ++kf) {
                    short8 x0 = *(const short8*)&xT[tt][l15][kf * 32 + q * 8];
                    short8 x1 = *(const short8*)&xT[tt][16 + l15][kf * 32 + q * 8];
                    aA0 = __builtin_amdgcn_mfma_f32_16x16x32_bf16(waf[kf], x0, aA0, 0, 0, 0);
                    aA1 = __builtin_amdgcn_mfma_f32_16x16x32_bf16(waf[kf], x1, aA1, 0, 0, 0);
                    aB0 = __builtin_amdgcn_mfma_f32_16x16x32_bf16(wbf[kf], x0, aB0, 0, 0, 0);
                    aB1 = __builtin_amdgcn_mfma_f32_16x16x32_bf16(wbf[kf], x1, aB1, 0, 0, 0);
                }
                ushort4v pa0, pa1, pb0, pb1;
                #pragma unroll
                for (int r = 0; r < 4; ++r) {
                    pa0[r] = f2bf(aA0[r] + ba_r[r]);
                    pa1[r] = f2bf(aA1[r] + ba_r[r]);
                    pb0[r] = f2bf(aB0[r] + bb_r[r]);
                    pb1[r] = f2bf(aB1[r] + bb_r[r]);
                }
                int kb = tt * 16 + q * 4;   // k slot = tt*16 + ci, ci = q*4+r
                *(ushort4v*)&asT[w][l15][kb]      = pa0;
                *(ushort4v*)&asT[w][16 + l15][kb] = pa1;
                *(ushort4v*)&bsT[w][l15][kb]      = pb0;
                *(ushort4v*)&bsT[w][16 + l15][kb] = pb1;
            }
        } else if (emit) {
            // wave 3 (idle in stage 1): emit x_pad[n][t][c][32] from xT.
            const int c = lane;
            #pragma unroll
            for (int tt = 0; tt < 4; ++tt) {
                u16* dst = xpad + pbase + (size_t)tt * 2048 + c * 32;
                #pragma unroll
                for (int b = 0; b < 4; ++b) {
                    short8 ov;
                    #pragma unroll
                    for (int u = 0; u < 8; ++u)
                        ov[u] = (short)xT[tt][b * 8 + u][c];
                    *(short8*)(dst + b * 8) = ov;
                }
            }
        }
        __syncthreads();   // stage1 done: asT/bsT ready, xT free for next group
        // Stage 2: S_i += a^T b over this group's K=64. Wave -> (mt,nt) combo.
        const int mt = w >> 1, nt = w & 1;
        #pragma unroll
        for (int i = 0; i < 3; ++i) {
            #pragma unroll
            for (int ks = 0; ks < 2; ++ks) {
                short8 af  = *(const short8*)&asT[i][mt * 16 + l15][ks * 32 + q * 8];
                short8 bf_ = *(const short8*)&bsT[i][nt * 16 + l15][ks * 32 + q * 8];
                accS[i] = __builtin_amdgcn_mfma_f32_16x16x32_bf16(af, bf_, accS[i], 0, 0, 0);
            }
        }
        // next iteration's xT writes are safe: stage1 reads finished before the
        // barrier above; stage2 touches only asT/bsT, ordered by the next barrier.
    }
    const int mt = w >> 1, nt = w & 1;
    #pragma unroll
    for (int i = 0; i < 3; ++i) {
        #pragma unroll
        for (int r = 0; r < 4; ++r) {
            int u = mt * 16 + q * 4 + r;
            int v = nt * 16 + l15;
            if (u < 25 && v < 25)
                atomicAdd(&Sws[(i * 64 + n) * 625 + u * 25 + v], accS[i][r]);
        }
    }
}

// ---------------- Kernel S: softmax over u (dim -2), + A_static + graph_attn ----------------
__global__ __launch_bounds__(64) void kS(float* __restrict__ Sws,
    const float* __restrict__ Ast, const float* __restrict__ Gat)
{
    int g = blockIdx.x;       // g = i*64 + n
    int i = g >> 6;
    int v = threadIdx.x;
    if (v >= 25) return;
    float vals[25];
    float m = -1e30f;
    #pragma unroll
    for (int u = 0; u < 25; ++u) {
        float s = Sws[g * 625 + u * 25 + v] * (1.0f / 4800.0f);
        vals[u] = s;
        m = fmaxf(m, s);
    }
    float sum = 0.f;
    #pragma unroll
    for (int u = 0; u < 25; ++u) { float e = __expf(vals[u] - m); vals[u] = e; sum += e; }
    float isum = 1.f / sum;
    #pragma unroll
    for (int u = 0; u < 25; ++u) {
        int idx = i * 625 + u * 25 + v;
        Sws[g * 625 + u * 25 + v] = vals[u] * isum + Ast[idx] + Gat[idx];
    }
}

// ---------------- Kernel B2: round-1 kB with A-frags/residual from xpad ----------------
// grid (25, 64), block 256. 12 t's per block. LDS = 12800 + 6144 = 18944 B.
__global__ __launch_bounds__(256, 4) void kB2(
    const float* __restrict__ Wgp, const float* __restrict__ bgp,
    const float* __restrict__ gam, const float* __restrict__ bet, const float* __restrict__ rmu,
    const float* __restrict__ rva, const float* __restrict__ attnw, const u16* __restrict__ xpad,
    float* __restrict__ outg)
{
    __shared__ u16 ysT[32][200];     // Ycat^T : [v][k=i*64+c]
    __shared__ u16 pTs[3][32][32];   // attn^T : [i][v][u], zero-padded
    const int tid  = threadIdx.x;
    const int lane = tid & 63;
    const int w    = tid >> 6;
    const int l15  = lane & 15;
    const int q    = lane >> 4;
    const int n    = blockIdx.y;
    const int t0   = blockIdx.x * 12;

    for (int e = tid; e < 3 * 32 * 32; e += 256) ((u16*)pTs)[e] = 0;
    __syncthreads();
    for (int e = tid; e < 1875; e += 256) {
        int i = e / 625;
        int r = e - i * 625;
        int u = r / 25;
        int v = r - u * 25;
        pTs[i][v][u] = f2bf(attnw[(i * 64 + n) * 625 + r]);
    }
    // Wg A-frags in registers for the whole kernel. A[m=o][k=i*64+c]
    short8 wgf[6];
    const int o_row = w * 16 + l15;
    #pragma unroll
    for (int kf = 0; kf < 6; ++kf) {
        int i  = kf >> 1;
        int c0 = (kf & 1) * 32 + q * 8;
        const float* p = Wgp + i * 4096 + o_row * 64 + c0;
        short8 f;
        #pragma unroll
        for (int j = 0; j < 8; ++j) f[j] = (short)f2bf(p[j]);
        wgf[kf] = f;
    }
    // BN constants per lane (o = w*16 + q*4 + r)
    float invr[4], add0r[4];
    #pragma unroll
    for (int r = 0; r < 4; ++r) {
        int o = w * 16 + q * 4 + r;
        float gv = gam[o], bt = bet[o], mu = rmu[o], vv = rva[o];
        float bgs = bgp[o] + bgp[64 + o] + bgp[128 + o];
        float iv = gv * rsqrtf(vv + 1e-5f);
        invr[r] = iv;
        add0r[r] = (bgs - mu) * iv + bt;
    }
    __syncthreads();
    // P B-frags in registers: B[k=u][n=v]
    short8 pf[3][2];
    #pragma unroll
    for (int i = 0; i < 3; ++i)
        #pragma unroll
        for (int nt = 0; nt < 2; ++nt)
            pf[i][nt] = *(const short8*)&pTs[i][nt * 16 + l15][q * 8];

    const u16* xpn = xpad + (size_t)n * 300 * 2048;
    float* ob = outg + (size_t)n * CTVB;

    for (int tl = 0; tl < 12; ++tl) {
        const int t = t0 + tl;
        const u16* xp = xpn + (size_t)t * 2048;   // x_pad[n][t][c][32], MFMA-ready
        // Phase A: Y_i = X_t @ P_i  (A = x strip per wave, K=u padded 32)
        short8 xf = *(const short8*)&xp[(w * 16 + l15) * 32 + q * 8];
        #pragma unroll
        for (int i = 0; i < 3; ++i) {
            #pragma unroll
            for (int nt = 0; nt < 2; ++nt) {
                float4v acc = {0, 0, 0, 0};
                acc = __builtin_amdgcn_mfma_f32_16x16x32_bf16(xf, pf[i][nt], acc, 0, 0, 0);
                ushort4v pk;
                #pragma unroll
                for (int r = 0; r < 4; ++r) pk[r] = f2bf(acc[r]);
                *(ushort4v*)&ysT[nt * 16 + l15][i * 64 + w * 16 + q * 4] = pk;
            }
        }
        __syncthreads();
        // Phase B: Out_t = WgCat(64x192) @ Ycat(192x25pad32)
        #pragma unroll
        for (int nt = 0; nt < 2; ++nt) {
            float4v acc = {0, 0, 0, 0};
            #pragma unroll
            for (int kf = 0; kf < 6; ++kf) {
                short8 yf = *(const short8*)&ysT[nt * 16 + l15][kf * 32 + q * 8];
                acc = __builtin_amdgcn_mfma_f32_16x16x32_bf16(wgf[kf], yf, acc, 0, 0, 0);
            }
            int v = nt * 16 + l15;
            if (v < 25) {
                #pragma unroll
                for (int r = 0; r < 4; ++r) {
                    int o = w * 16 + q * 4 + r;
                    float xres = bf2f(xp[o * 32 + v]);   // residual from the same hot block
                    float val = fmaf(acc[r], invr[r], add0r[r]) + xres;
                    val = fmaxf(val, 0.f);
                    ob[(size_t)o * TVB + t * 25 + v] = val;
                }
            }
        }
        __syncthreads();
    }
}

// ---------------- Kernel B (fallback only): round-1 version ----------------
__global__ __launch_bounds__(256, 4) void kB(
    const float* __restrict__ xg, const float* __restrict__ Wgp, const float* __restrict__ bgp,
    const float* __restrict__ gam, const float* __restrict__ bet, const float* __restrict__ rmu,
    const float* __restrict__ rva, const float* __restrict__ attnw, float* __restrict__ outg)
{
    __shared__ u16 xsu[4][64][40];
    __shared__ u16 ysT[32][200];
    __shared__ u16 pTs[3][32][32];
    const int tid  = threadIdx.x;
    const int lane = tid & 63;
    const int w    = tid >> 6;
    const int l15  = lane & 15;
    const int q    = lane >> 4;
    const int n    = blockIdx.y;
    const int t0   = blockIdx.x * 4;

    for (int e = tid; e < 3 * 32 * 32; e += 256) ((u16*)pTs)[e] = 0;
    const float* xb = xg + (size_t)n * CTVB;
    for (int e = tid; e < 1600; e += 256) {
        int c = e / 25;
        int j = e - c * 25;
        float4v xv = *(const float4v*)(xb + (size_t)c * TVB + t0 * 25 + j * 4);
        #pragma unroll
        for (int k = 0; k < 4; ++k) {
            int idx = j * 4 + k;
            int tt = idx / 25;
            int u  = idx - tt * 25;
            xsu[tt][c][u] = f2bf(xv[k]);
        }
    }
    for (int e = tid; e < 4 * 64 * 7; e += 256) {
        int tt = e / (64 * 7);
        int r  = e - tt * (64 * 7);
        xsu[tt][r / 7][25 + r % 7] = 0;
    }
    __syncthreads();
    for (int e = tid; e < 1875; e += 256) {
        int i = e / 625;
        int r = e - i * 625;
        int u = r / 25;
        int v = r - u * 25;
        pTs[i][v][u] = f2bf(attnw[(i * 64 + n) * 625 + r]);
    }
    short8 wgf[6];
    const int o_row = w * 16 + l15;
    #pragma unroll
    for (int kf = 0; kf < 6; ++kf) {
        int i  = kf >> 1;
        int c0 = (kf & 1) * 32 + q * 8;
        const float* p = Wgp + i * 4096 + o_row * 64 + c0;
        short8 f;
        #pragma unroll
        for (int j = 0; j < 8; ++j) f[j] = (short)f2bf(p[j]);
        wgf[kf] = f;
    }
    float invr[4], add0r[4];
    #pragma unroll
    for (int r = 0; r < 4; ++r) {
        int o = w * 16 + q * 4 + r;
        float gv = gam[o], bt = bet[o], mu = rmu[o], vv = rva[o];
        float bgs = bgp[o] + bgp[64 + o] + bgp[128 + o];
        float iv = gv * rsqrtf(vv + 1e-5f);
        invr[r] = iv;
        add0r[r] = (bgs - mu) * iv + bt;
    }
    __syncthreads();
    short8 pf[3][2];
    #pragma unroll
    for (int i = 0; i < 3; ++i)
        #pragma unroll
        for (int nt = 0; nt < 2; ++nt)
            pf[i][nt] = *(const short8*)&pTs[i][nt * 16 + l15][q * 8];

    for (int tl = 0; tl < 4; ++tl) {
        short8 xf = *(const short8*)&xsu[tl][w * 16 + l15][q * 8];
        #pragma unroll
        for (int i = 0; i < 3; ++i) {
            #pragma unroll
            for (int nt = 0; nt < 2; ++nt) {
                float4v acc = {0, 0, 0, 0};
                acc = __builtin_amdgcn_mfma_f32_16x16x32_bf16(xf, pf[i][nt], acc, 0, 0, 0);
                ushort4v pk;
                #pragma unroll
                for (int r = 0; r < 4; ++r) pk[r] = f2bf(acc[r]);
                *(ushort4v*)&ysT[nt * 16 + l15][i * 64 + w * 16 + q * 4] = pk;
            }
        }
        __syncthreads();
        #pragma unroll
        for (int nt = 0; nt < 2; ++nt) {
            float4v acc = {0, 0, 0, 0};
            #pragma unroll
            for (int kf = 0; kf < 6; ++kf) {
                short8 yf = *(const short8*)&ysT[nt * 16 + l15][kf * 32 + q * 8];
                acc = __builtin_amdgcn_mfma_f32_16x16x32_bf16(wgf[kf], yf, acc, 0, 0, 0);
            }
            int v = nt * 16 + l15;
            if (v < 25) {
                size_t obp = (size_t)n * CTVB + (size_t)(t0 + tl) * 25 + v;
                #pragma unroll
                for (int r = 0; r < 4; ++r) {
                    int o = w * 16 + q * 4 + r;
                    float xres = bf2f(xsu[tl][o][v]);
                    float val = fmaf(acc[r], invr[r], add0r[r]) + xres;
                    val = fmaxf(val, 0.f);
                    outg[obp + (size_t)o * TVB] = val;
                }
            }
        }
        __syncthreads();
    }
}

extern "C" void kernel_launch(void* const* d_in, const int* in_sizes, int n_in,
                              void* d_out, int out_size, void* d_ws, size_t ws_size,
                              hipStream_t stream) {
    const float* x    = (const float*)d_in[0];
    const float* Ast  = (const float*)d_in[1];
    const float* Gat  = (const float*)d_in[2];
    const float* Wg   = (const float*)d_in[3];
    const float* bg   = (const float*)d_in[4];
    const float* Wa   = (const float*)d_in[5];
    const float* ba   = (const float*)d_in[6];
    const float* Wb   = (const float*)d_in[7];
    const float* bb   = (const float*)d_in[8];
    const float* gam  = (const float*)d_in[9];
    const float* bet  = (const float*)d_in[10];
    const float* rmu  = (const float*)d_in[11];
    const float* rva  = (const float*)d_in[12];
    float* out = (float*)d_out;
    float* Sws = (float*)d_ws;   // 192*625 floats = 480 KB

    const size_t need = (size_t)XPAD_OFF + XPAD_U16 * 2;
    hipMemsetAsync(Sws, 0, 192 * 625 * sizeof(float), stream);
    if (ws_size >= need) {
        u16* xpad = (u16*)((char*)d_ws + XPAD_OFF);
        kA<<<dim3(15, 64), 256, 0, stream>>>(x, Wa, ba, Wb, bb, Sws, xpad);
        kS<<<dim3(192), 64, 0, stream>>>(Sws, Ast, Gat);
        kB2<<<dim3(25, 64), 256, 0, stream>>>(Wg, bg, gam, bet, rmu, rva, Sws, xpad, out);
    } else {
        kA<<<dim3(15, 64), 256, 0, stream>>>(x, Wa, ba, Wb, bb, Sws, nullptr);
        kS<<<dim3(192), 64, 0, stream>>>(Sws, Ast, Gat);
        kB<<<dim3(75, 64), 256, 0, stream>>>(x, Wg, bg, gam, bet, rmu, rva, Sws, out);
    }
}